// Round 2
// baseline (356.396 us; speedup 1.0000x reference)
//
#include <hip/hip_runtime.h>

#define NN 50000      // N_ENT
#define NR 100        // N_REL2
#define NB 16         // N_BASES
#define D  64         // DIM
#define NE 100000     // N_EDGES

#define EB 1024                      // edge kernel blocks (4 waves each)
#define EW (EB * 4)                  // 4096 edge waves
#define EPW ((NE + EW - 1) / EW)     // 25 edges per wave

#define NBK 392                      // node kernel blocks
#define NW (NBK * 4)                 // 1568 node waves
#define NPW ((NN + NW - 1) / NW)     // 32 nodes per wave

__device__ __forceinline__ int rfl(int v) { return __builtin_amdgcn_readfirstlane(v); }

// W[r, k, d] = sum_b att[r, b] * basis[b, k, d]   (coalesced in and out)
__global__ __launch_bounds__(256) void compute_w(
    const float* __restrict__ att, const float* __restrict__ basis,
    float* __restrict__ W)
{
    int idx = blockIdx.x * 256 + threadIdx.x;      // over NR*D*D = 409600
    if (idx >= NR * D * D) return;
    int r  = idx / (D * D);
    int kd = idx - r * (D * D);
    float acc = 0.f;
#pragma unroll
    for (int b = 0; b < NB; ++b)
        acc += att[r * NB + b] * basis[b * D * D + kd];
    W[idx] = acc;
}

// x0[n, d] = emb[entity[n], d]
__global__ __launch_bounds__(256) void gather_emb(
    const int* __restrict__ entity, const float* __restrict__ emb,
    float* __restrict__ x0)
{
    int idx = blockIdx.x * 256 + threadIdx.x;
    if (idx >= NN * D) return;
    int n = idx >> 6;
    int d = idx & 63;
    x0[idx] = emb[entity[n] * D + d];
}

// per-relation histogram + per-node in-degree, one pass
__global__ __launch_bounds__(256) void prep(
    const int* __restrict__ et, const int* __restrict__ dst,
    int* __restrict__ relCnt, float* __restrict__ cnt)
{
    int e = blockIdx.x * 256 + threadIdx.x;
    if (e >= NE) return;
    atomicAdd(&relCnt[et[e]], 1);
    atomicAdd(&cnt[dst[e]], 1.0f);
}

// serial 100-element exclusive scan (one lane), writes offs + cursor copy
__global__ void scan_rel(const int* __restrict__ relCnt,
                         int* __restrict__ offs, int* __restrict__ cursor)
{
    if (threadIdx.x == 0) {
        int acc = 0;
        for (int r = 0; r < NR; ++r) { offs[r] = acc; cursor[r] = acc; acc += relCnt[r]; }
        offs[NR] = acc;
    }
}

// counting-sort scatter: edges grouped by relation
__global__ __launch_bounds__(256) void scatter_edges(
    const int* __restrict__ src, const int* __restrict__ dst,
    const int* __restrict__ et, const float* __restrict__ en,
    int* __restrict__ cursor, int* __restrict__ srcS, int* __restrict__ dstS,
    int* __restrict__ rS, float* __restrict__ normS)
{
    int e = blockIdx.x * 256 + threadIdx.x;
    if (e >= NE) return;
    int r = et[e];
    int p = atomicAdd(&cursor[r], 1);
    srcS[p] = src[e]; dstS[p] = dst[e]; rS[p] = r; normS[p] = en[e];
}

// One wave per run of sorted edges. W column (for output dim = lane) lives in
// 64 VGPRs, loaded once per relation segment. x-row broadcast via v_readlane.
__global__ __launch_bounds__(256) void edge_sorted(
    const int* __restrict__ srcS, const int* __restrict__ dstS,
    const int* __restrict__ rS, const float* __restrict__ normS,
    const int* __restrict__ offs, const float* __restrict__ x,
    const float* __restrict__ W, float* __restrict__ s)
{
    int wave = blockIdx.x * 4 + (threadIdx.x >> 6);
    int lane = threadIdx.x & 63;
    int e    = wave * EPW;
    int eend = e + EPW < NE ? e + EPW : NE;

    while (e < eend) {
        int r = rfl(rS[e]);
        int oEnd = offs[r + 1];
        int segEnd = oEnd < eend ? oEnd : eend;

        const float* __restrict__ Wr = W + (size_t)r * (D * D);
        float ww[64];
#pragma unroll
        for (int k = 0; k < 64; ++k) ww[k] = Wr[k * 64 + lane];   // coalesced 256B per k

        // software pipeline: prefetch x row one edge ahead
        int sn  = rfl(srcS[e]);
        int xvi = __float_as_int(x[(size_t)sn * 64 + lane]);
        while (e < segEnd) {
            float nrm = normS[e];
            int dn = rfl(dstS[e]);
            int xcur = xvi;
            int en = e + 1;
            if (en < segEnd) {
                int sn2 = rfl(srcS[en]);
                xvi = __float_as_int(x[(size_t)sn2 * 64 + lane]);
            }
            float a0 = 0.f, a1 = 0.f, a2 = 0.f, a3 = 0.f;
#pragma unroll
            for (int k = 0; k < 64; k += 4) {
                a0 = fmaf(__int_as_float(__builtin_amdgcn_readlane(xcur, k)),     ww[k],     a0);
                a1 = fmaf(__int_as_float(__builtin_amdgcn_readlane(xcur, k + 1)), ww[k + 1], a1);
                a2 = fmaf(__int_as_float(__builtin_amdgcn_readlane(xcur, k + 2)), ww[k + 2], a2);
                a3 = fmaf(__int_as_float(__builtin_amdgcn_readlane(xcur, k + 3)), ww[k + 3], a3);
            }
            atomicAdd(&s[(size_t)dn * 64 + lane], ((a0 + a1) + (a2 + a3)) * nrm);
            e = en;
        }
    }
}

// out[n] = s[n]/max(cnt,1) + x[n]@root + bias.  root column in VGPRs per wave.
__global__ __launch_bounds__(256) void node_rl(
    const float* __restrict__ x, const float* __restrict__ s,
    const float* __restrict__ cnt, const float* __restrict__ root,
    const float* __restrict__ bias, float* __restrict__ out)
{
    int wave = blockIdx.x * 4 + (threadIdx.x >> 6);
    int lane = threadIdx.x & 63;

    float rr[64];
#pragma unroll
    for (int k = 0; k < 64; ++k) rr[k] = root[k * 64 + lane];
    float bv = bias[lane];

    int n  = wave * NPW;
    int n1 = n + NPW < NN ? n + NPW : NN;
    for (; n < n1; ++n) {
        int xvi = __float_as_int(x[(size_t)n * 64 + lane]);
        float a0 = 0.f, a1 = 0.f, a2 = 0.f, a3 = 0.f;
#pragma unroll
        for (int k = 0; k < 64; k += 4) {
            a0 = fmaf(__int_as_float(__builtin_amdgcn_readlane(xvi, k)),     rr[k],     a0);
            a1 = fmaf(__int_as_float(__builtin_amdgcn_readlane(xvi, k + 1)), rr[k + 1], a1);
            a2 = fmaf(__int_as_float(__builtin_amdgcn_readlane(xvi, k + 2)), rr[k + 2], a2);
            a3 = fmaf(__int_as_float(__builtin_amdgcn_readlane(xvi, k + 3)), rr[k + 3], a3);
        }
        float c = cnt[n];
        c = c > 1.f ? c : 1.f;
        out[(size_t)n * 64 + lane] =
            s[(size_t)n * 64 + lane] / c + ((a0 + a1) + (a2 + a3)) + bv;
    }
}

extern "C" void kernel_launch(void* const* d_in, const int* in_sizes, int n_in,
                              void* d_out, int out_size, void* d_ws, size_t ws_size,
                              hipStream_t stream) {
    const int*   entity    = (const int*)d_in[0];
    const int*   edge_index= (const int*)d_in[1];    // [2, NE]
    const int*   edge_type = (const int*)d_in[2];
    const float* edge_norm = (const float*)d_in[3];
    const float* emb       = (const float*)d_in[4];
    const float* basis1    = (const float*)d_in[5];
    const float* att1      = (const float*)d_in[6];
    const float* root1     = (const float*)d_in[7];
    const float* bias1     = (const float*)d_in[8];
    const float* basis2    = (const float*)d_in[9];
    const float* att2      = (const float*)d_in[10];
    const float* root2     = (const float*)d_in[11];
    const float* bias2     = (const float*)d_in[12];

    const int* src = edge_index;
    const int* dst = edge_index + NE;

    float* ws    = (float*)d_ws;
    float* x0    = ws;                       // NN*D
    float* s     = x0   + (size_t)NN * D;    // NN*D
    float* cnt   = s    + (size_t)NN * D;    // NN
    int*   relCnt= (int*)(cnt + NN);         // NR
    int*   offs  = relCnt + NR;              // NR+1
    int*   cursor= offs + NR + 1;            // NR
    int*   srcS  = cursor + NR;              // NE
    int*   dstS  = srcS + NE;                // NE
    int*   rS    = dstS + NE;                // NE
    float* normS = (float*)(rS + NE);        // NE
    float* W     = normS + NE;               // NR*D*D

    float* out = (float*)d_out;

    // zero s + cnt + relCnt (contiguous)
    hipMemsetAsync(s, 0, ((size_t)NN * D + NN) * sizeof(float) + NR * sizeof(int), stream);

    gather_emb<<<(NN * D + 255) / 256, 256, 0, stream>>>(entity, emb, x0);
    prep<<<(NE + 255) / 256, 256, 0, stream>>>(edge_type, dst, relCnt, cnt);
    scan_rel<<<1, 64, 0, stream>>>(relCnt, offs, cursor);
    scatter_edges<<<(NE + 255) / 256, 256, 0, stream>>>(src, dst, edge_type, edge_norm,
                                                        cursor, srcS, dstS, rS, normS);

    // ---- layer 1 ----
    compute_w<<<(NR * D * D + 255) / 256, 256, 0, stream>>>(att1, basis1, W);
    edge_sorted<<<EB, 256, 0, stream>>>(srcS, dstS, rS, normS, offs, x0, W, s);
    node_rl<<<NBK, 256, 0, stream>>>(x0, s, cnt, root1, bias1, out);

    // ---- layer 2 ----
    hipMemsetAsync(s, 0, (size_t)NN * D * sizeof(float), stream);
    compute_w<<<(NR * D * D + 255) / 256, 256, 0, stream>>>(att2, basis2, W);
    edge_sorted<<<EB, 256, 0, stream>>>(srcS, dstS, rS, normS, offs, out, W, s);
    node_rl<<<NBK, 256, 0, stream>>>(out, s, cnt, root2, bias2, out);
}

// Round 3
// 180.630 us; speedup vs baseline: 1.9731x; 1.9731x over previous
//
#include <hip/hip_runtime.h>

#define NN 50000      // N_ENT
#define NR 100        // N_REL2
#define NB 16         // N_BASES
#define D  64         // DIM
#define NE 100000     // N_EDGES

#define HB  196       // histogram/scatter blocks
#define EPB 512       // edges per block (HB*EPB = 100352 >= NE)

#define EB 1024                      // edge kernel blocks (4 waves each)
#define EW (EB * 4)                  // 4096 edge waves
#define EPW ((NE + EW - 1) / EW)     // 25 edges per wave

#define NBK 392                      // node kernel blocks
#define NW (NBK * 4)                 // 1568 node waves
#define NPW ((NN + NW - 1) / NW)     // 32 nodes per wave

__device__ __forceinline__ int rfl(int v) { return __builtin_amdgcn_readfirstlane(v); }

// W[r, k, d] = sum_b att[r, b] * basis[b, k, d]   (coalesced in and out)
__global__ __launch_bounds__(256) void compute_w(
    const float* __restrict__ att, const float* __restrict__ basis,
    float* __restrict__ W)
{
    int idx = blockIdx.x * 256 + threadIdx.x;      // over NR*D*D = 409600
    if (idx >= NR * D * D) return;
    int r  = idx / (D * D);
    int kd = idx - r * (D * D);
    float acc = 0.f;
#pragma unroll
    for (int b = 0; b < NB; ++b)
        acc += att[r * NB + b] * basis[b * D * D + kd];
    W[idx] = acc;
}

// x0[n, :] = emb[entity[n], :]  (float4 vectorized)
__global__ __launch_bounds__(256) void gather_emb(
    const int* __restrict__ entity, const float4* __restrict__ emb4,
    float4* __restrict__ x04)
{
    int idx = blockIdx.x * 256 + threadIdx.x;      // over NN*16
    if (idx >= NN * 16) return;
    int n = idx >> 4;
    int q = idx & 15;
    x04[idx] = emb4[(size_t)entity[n] * 16 + q];
}

// Pass 1: per-block relation histogram (LDS atomics) + node in-degree
__global__ __launch_bounds__(256) void hist_edges(
    const int* __restrict__ et, const int* __restrict__ dst,
    int* __restrict__ blockHist, float* __restrict__ cnt)
{
    __shared__ int lh[NR];
    for (int i = threadIdx.x; i < NR; i += 256) lh[i] = 0;
    __syncthreads();
#pragma unroll
    for (int i = 0; i < EPB / 256; ++i) {
        int e = blockIdx.x * EPB + i * 256 + threadIdx.x;
        if (e < NE) {
            atomicAdd(&lh[et[e]], 1);
            atomicAdd(&cnt[dst[e]], 1.0f);
        }
    }
    __syncthreads();
    for (int i = threadIdx.x; i < NR; i += 256)
        blockHist[blockIdx.x * NR + i] = lh[i];
}

// Pass 2: column scan -> per-(block,rel) bases + global relation offsets
__global__ void scan_blocks(const int* __restrict__ blockHist,
                            int* __restrict__ blockBase, int* __restrict__ offs)
{
    __shared__ int totL[NR];
    __shared__ int offsL[NR];
    int r = threadIdx.x;
    if (r < NR) {
        int tot = 0;
        for (int b = 0; b < HB; ++b) tot += blockHist[b * NR + r];
        totL[r] = tot;
    }
    __syncthreads();
    if (threadIdx.x == 0) {
        int acc = 0;
        for (int i = 0; i < NR; ++i) { offsL[i] = acc; acc += totL[i]; }
    }
    __syncthreads();
    if (r < NR) {
        int acc = offsL[r];
        for (int b = 0; b < HB; ++b) { blockBase[b * NR + r] = acc; acc += blockHist[b * NR + r]; }
        offs[r] = offsL[r];
        if (r == 0) offs[NR] = NE;
    }
}

// Pass 3: scatter edges into relation-sorted arrays (LDS cursors only)
__global__ __launch_bounds__(256) void scatter_sorted(
    const int* __restrict__ src, const int* __restrict__ dst,
    const int* __restrict__ et, const float* __restrict__ en,
    const int* __restrict__ blockBase, int* __restrict__ srcS,
    int* __restrict__ dstS, int* __restrict__ rS, float* __restrict__ normS)
{
    __shared__ int lcur[NR];
    for (int i = threadIdx.x; i < NR; i += 256)
        lcur[i] = blockBase[blockIdx.x * NR + i];
    __syncthreads();
#pragma unroll
    for (int i = 0; i < EPB / 256; ++i) {
        int e = blockIdx.x * EPB + i * 256 + threadIdx.x;
        if (e < NE) {
            int r = et[e];
            int p = atomicAdd(&lcur[r], 1);
            srcS[p] = src[e]; dstS[p] = dst[e]; rS[p] = r; normS[p] = en[e];
        }
    }
}

// One wave per run of sorted edges. W column (for output dim = lane) lives in
// 64 VGPRs, loaded once per relation segment. x-row broadcast via v_readlane.
__global__ __launch_bounds__(256) void edge_sorted(
    const int* __restrict__ srcS, const int* __restrict__ dstS,
    const int* __restrict__ rS, const float* __restrict__ normS,
    const int* __restrict__ offs, const float* __restrict__ x,
    const float* __restrict__ W, float* __restrict__ s)
{
    int wave = blockIdx.x * 4 + (threadIdx.x >> 6);
    int lane = threadIdx.x & 63;
    int e    = wave * EPW;
    int eend = e + EPW < NE ? e + EPW : NE;

    while (e < eend) {
        int r = rfl(rS[e]);
        int oEnd = offs[r + 1];
        int segEnd = oEnd < eend ? oEnd : eend;

        const float* __restrict__ Wr = W + (size_t)r * (D * D);
        float ww[64];
#pragma unroll
        for (int k = 0; k < 64; ++k) ww[k] = Wr[k * 64 + lane];   // coalesced 256B per k

        // software pipeline: prefetch x row one edge ahead
        int sn  = rfl(srcS[e]);
        int xvi = __float_as_int(x[(size_t)sn * 64 + lane]);
        while (e < segEnd) {
            float nrm = normS[e];
            int dn = rfl(dstS[e]);
            int xcur = xvi;
            int en = e + 1;
            if (en < segEnd) {
                int sn2 = rfl(srcS[en]);
                xvi = __float_as_int(x[(size_t)sn2 * 64 + lane]);
            }
            float a0 = 0.f, a1 = 0.f, a2 = 0.f, a3 = 0.f;
#pragma unroll
            for (int k = 0; k < 64; k += 4) {
                a0 = fmaf(__int_as_float(__builtin_amdgcn_readlane(xcur, k)),     ww[k],     a0);
                a1 = fmaf(__int_as_float(__builtin_amdgcn_readlane(xcur, k + 1)), ww[k + 1], a1);
                a2 = fmaf(__int_as_float(__builtin_amdgcn_readlane(xcur, k + 2)), ww[k + 2], a2);
                a3 = fmaf(__int_as_float(__builtin_amdgcn_readlane(xcur, k + 3)), ww[k + 3], a3);
            }
            atomicAdd(&s[(size_t)dn * 64 + lane], ((a0 + a1) + (a2 + a3)) * nrm);
            e = en;
        }
    }
}

// out[n] = s[n]/max(cnt,1) + x[n]@root + bias.  root column in VGPRs per wave.
__global__ __launch_bounds__(256) void node_rl(
    const float* __restrict__ x, const float* __restrict__ s,
    const float* __restrict__ cnt, const float* __restrict__ root,
    const float* __restrict__ bias, float* __restrict__ out)
{
    int wave = blockIdx.x * 4 + (threadIdx.x >> 6);
    int lane = threadIdx.x & 63;

    float rr[64];
#pragma unroll
    for (int k = 0; k < 64; ++k) rr[k] = root[k * 64 + lane];
    float bv = bias[lane];

    int n  = wave * NPW;
    int n1 = n + NPW < NN ? n + NPW : NN;
    for (; n < n1; ++n) {
        int xvi = __float_as_int(x[(size_t)n * 64 + lane]);
        float a0 = 0.f, a1 = 0.f, a2 = 0.f, a3 = 0.f;
#pragma unroll
        for (int k = 0; k < 64; k += 4) {
            a0 = fmaf(__int_as_float(__builtin_amdgcn_readlane(xvi, k)),     rr[k],     a0);
            a1 = fmaf(__int_as_float(__builtin_amdgcn_readlane(xvi, k + 1)), rr[k + 1], a1);
            a2 = fmaf(__int_as_float(__builtin_amdgcn_readlane(xvi, k + 2)), rr[k + 2], a2);
            a3 = fmaf(__int_as_float(__builtin_amdgcn_readlane(xvi, k + 3)), rr[k + 3], a3);
        }
        float c = cnt[n];
        c = c > 1.f ? c : 1.f;
        out[(size_t)n * 64 + lane] =
            s[(size_t)n * 64 + lane] / c + ((a0 + a1) + (a2 + a3)) + bv;
    }
}

extern "C" void kernel_launch(void* const* d_in, const int* in_sizes, int n_in,
                              void* d_out, int out_size, void* d_ws, size_t ws_size,
                              hipStream_t stream) {
    const int*   entity    = (const int*)d_in[0];
    const int*   edge_index= (const int*)d_in[1];    // [2, NE]
    const int*   edge_type = (const int*)d_in[2];
    const float* edge_norm = (const float*)d_in[3];
    const float* emb       = (const float*)d_in[4];
    const float* basis1    = (const float*)d_in[5];
    const float* att1      = (const float*)d_in[6];
    const float* root1     = (const float*)d_in[7];
    const float* bias1     = (const float*)d_in[8];
    const float* basis2    = (const float*)d_in[9];
    const float* att2      = (const float*)d_in[10];
    const float* root2     = (const float*)d_in[11];
    const float* bias2     = (const float*)d_in[12];

    const int* src = edge_index;
    const int* dst = edge_index + NE;

    float* ws      = (float*)d_ws;
    float* x0      = ws;                         // NN*D
    float* s       = x0   + (size_t)NN * D;      // NN*D
    float* cnt     = s    + (size_t)NN * D;      // NN
    int*   offs    = (int*)(cnt + NN);           // NR+1
    int*   blockHist = offs + NR + 1;            // HB*NR
    int*   blockBase = blockHist + HB * NR;      // HB*NR
    int*   srcS    = blockBase + HB * NR;        // NE
    int*   dstS    = srcS + NE;                  // NE
    int*   rS      = dstS + NE;                  // NE
    float* normS   = (float*)(rS + NE);          // NE
    float* W       = normS + NE;                 // NR*D*D

    float* out = (float*)d_out;

    // zero s + cnt (contiguous)
    hipMemsetAsync(s, 0, ((size_t)NN * D + NN) * sizeof(float), stream);

    gather_emb<<<(NN * 16 + 255) / 256, 256, 0, stream>>>(
        entity, (const float4*)emb, (float4*)x0);
    hist_edges<<<HB, 256, 0, stream>>>(edge_type, dst, blockHist, cnt);
    scan_blocks<<<1, 128, 0, stream>>>(blockHist, blockBase, offs);
    scatter_sorted<<<HB, 256, 0, stream>>>(src, dst, edge_type, edge_norm,
                                           blockBase, srcS, dstS, rS, normS);

    // ---- layer 1 ----
    compute_w<<<(NR * D * D + 255) / 256, 256, 0, stream>>>(att1, basis1, W);
    edge_sorted<<<EB, 256, 0, stream>>>(srcS, dstS, rS, normS, offs, x0, W, s);
    node_rl<<<NBK, 256, 0, stream>>>(x0, s, cnt, root1, bias1, out);

    // ---- layer 2 ----
    hipMemsetAsync(s, 0, (size_t)NN * D * sizeof(float), stream);
    compute_w<<<(NR * D * D + 255) / 256, 256, 0, stream>>>(att2, basis2, W);
    edge_sorted<<<EB, 256, 0, stream>>>(srcS, dstS, rS, normS, offs, out, W, s);
    node_rl<<<NBK, 256, 0, stream>>>(out, s, cnt, root2, bias2, out);
}

// Round 4
// 176.489 us; speedup vs baseline: 2.0194x; 1.0235x over previous
//
#include <hip/hip_runtime.h>

#define NN 50000      // N_ENT
#define NR 100        // N_REL2
#define NB 16         // N_BASES
#define D  64         // DIM
#define NE 100000     // N_EDGES

#define HB  196       // histogram/scatter blocks
#define EPB 512       // edges per block

#define EB 1024                      // edge kernel blocks (4 waves each)
#define EW (EB * 4)                  // 4096 edge waves
#define EPW ((NE + EW - 1) / EW)     // 25 edges per wave

#define NBK 392                      // node kernel blocks
#define NW (NBK * 4)                 // 1568 node waves
#define NPW ((NN + NW - 1) / NW)     // 32 nodes per wave

typedef float f32x4 __attribute__((ext_vector_type(4)));

__device__ __forceinline__ int rfl(int v) { return __builtin_amdgcn_readfirstlane(v); }
#define PIN(x) asm volatile("" : "+v"(x))

// Fused weight prep. Blocks 0..199: Wt[layer][r][d][k] = sum_b att[r,b]*basis[b,k,d]
// (transposed via padded-LDS). Blocks 200..201: rT[d][k] = root[k][d].
__global__ __launch_bounds__(256) void compute_wt(
    const float* __restrict__ att1, const float* __restrict__ basis1,
    const float* __restrict__ root1,
    const float* __restrict__ att2, const float* __restrict__ basis2,
    const float* __restrict__ root2,
    float* __restrict__ Wt1, float* __restrict__ Wt2,
    float* __restrict__ rT1, float* __restrict__ rT2)
{
    __shared__ float t[64 * 65];
    int b = blockIdx.x;
    if (b < 2 * NR) {
        int layer = b >= NR;
        int r = layer ? b - NR : b;
        const float* att   = layer ? att2 : att1;
        const float* basis = layer ? basis2 : basis1;
        float*       Wt    = layer ? Wt2 : Wt1;
        float a[NB];
#pragma unroll
        for (int bb = 0; bb < NB; ++bb) a[bb] = att[r * NB + bb];
#pragma unroll
        for (int i = 0; i < 16; ++i) {
            int idx = i * 256 + threadIdx.x;        // [k][d] linear
            float acc = 0.f;
#pragma unroll
            for (int bb = 0; bb < NB; ++bb) acc += a[bb] * basis[bb * 4096 + idx];
            t[(idx >> 6) * 65 + (idx & 63)] = acc;  // t[k][d], padded
        }
        __syncthreads();
#pragma unroll
        for (int i = 0; i < 16; ++i) {
            int j = i * 256 + threadIdx.x;          // [d][k] linear
            Wt[(size_t)r * 4096 + j] = t[(j & 63) * 65 + (j >> 6)];
        }
    } else {
        const float* root = (b == 2 * NR) ? root1 : root2;
        float*       rT   = (b == 2 * NR) ? rT1 : rT2;
#pragma unroll
        for (int i = 0; i < 16; ++i) {
            int idx = i * 256 + threadIdx.x;
            t[(idx >> 6) * 65 + (idx & 63)] = root[idx];
        }
        __syncthreads();
#pragma unroll
        for (int i = 0; i < 16; ++i) {
            int j = i * 256 + threadIdx.x;
            rT[j] = t[(j & 63) * 65 + (j >> 6)];
        }
    }
}

// x0[n, :] = emb[entity[n], :]  (float4 vectorized)
__global__ __launch_bounds__(256) void gather_emb(
    const int* __restrict__ entity, const f32x4* __restrict__ emb4,
    f32x4* __restrict__ x04)
{
    int idx = blockIdx.x * 256 + threadIdx.x;      // over NN*16
    if (idx >= NN * 16) return;
    int n = idx >> 4;
    int q = idx & 15;
    x04[idx] = emb4[(size_t)entity[n] * 16 + q];
}

// Pass 1: per-block relation histogram (LDS atomics) + node in-degree
__global__ __launch_bounds__(256) void hist_edges(
    const int* __restrict__ et, const int* __restrict__ dst,
    int* __restrict__ blockHist, float* __restrict__ cnt)
{
    __shared__ int lh[NR];
    for (int i = threadIdx.x; i < NR; i += 256) lh[i] = 0;
    __syncthreads();
#pragma unroll
    for (int i = 0; i < EPB / 256; ++i) {
        int e = blockIdx.x * EPB + i * 256 + threadIdx.x;
        if (e < NE) {
            atomicAdd(&lh[et[e]], 1);
            atomicAdd(&cnt[dst[e]], 1.0f);
        }
    }
    __syncthreads();
    for (int i = threadIdx.x; i < NR; i += 256)
        blockHist[blockIdx.x * NR + i] = lh[i];
}

// Pass 2: column scan -> per-(block,rel) bases + global relation offsets
__global__ void scan_blocks(const int* __restrict__ blockHist,
                            int* __restrict__ blockBase, int* __restrict__ offs)
{
    __shared__ int totL[NR];
    __shared__ int offsL[NR];
    int r = threadIdx.x;
    if (r < NR) {
        int tot = 0;
        for (int b = 0; b < HB; ++b) tot += blockHist[b * NR + r];
        totL[r] = tot;
    }
    __syncthreads();
    if (threadIdx.x == 0) {
        int acc = 0;
        for (int i = 0; i < NR; ++i) { offsL[i] = acc; acc += totL[i]; }
    }
    __syncthreads();
    if (r < NR) {
        int acc = offsL[r];
        for (int b = 0; b < HB; ++b) { blockBase[b * NR + r] = acc; acc += blockHist[b * NR + r]; }
        offs[r] = offsL[r];
        if (r == 0) offs[NR] = NE;
    }
}

// Pass 3: scatter edges into relation-sorted arrays (LDS cursors only)
__global__ __launch_bounds__(256) void scatter_sorted(
    const int* __restrict__ src, const int* __restrict__ dst,
    const int* __restrict__ et, const float* __restrict__ en,
    const int* __restrict__ blockBase, int* __restrict__ srcS,
    int* __restrict__ dstS, int* __restrict__ rS, float* __restrict__ normS)
{
    __shared__ int lcur[NR];
    for (int i = threadIdx.x; i < NR; i += 256)
        lcur[i] = blockBase[blockIdx.x * NR + i];
    __syncthreads();
#pragma unroll
    for (int i = 0; i < EPB / 256; ++i) {
        int e = blockIdx.x * EPB + i * 256 + threadIdx.x;
        if (e < NE) {
            int r = et[e];
            int p = atomicAdd(&lcur[r], 1);
            srcS[p] = src[e]; dstS[p] = dst[e]; rS[p] = r; normS[p] = en[e];
        }
    }
}

// One wave per run of sorted edges. W column (output dim = lane) pinned in 16
// f32x4 VGPRs via asm (prevents remat/reload). x-row broadcast via v_readlane.
__global__ __launch_bounds__(256, 4) void edge_reg(
    const int* __restrict__ srcS, const int* __restrict__ dstS,
    const int* __restrict__ rS, const float* __restrict__ normS,
    const int* __restrict__ offs, const float* __restrict__ x,
    const float* __restrict__ Wt, float* __restrict__ s)
{
    int wave = blockIdx.x * 4 + (threadIdx.x >> 6);
    int lane = threadIdx.x & 63;
    int e0 = wave * EPW;
    if (e0 >= NE) return;
    int eend = e0 + EPW < NE ? e0 + EPW : NE;

    // batch this wave's edge meta into lanes (lane i holds edge e0+i)
    int ei = e0 + lane; if (ei > NE - 1) ei = NE - 1;
    int srcv = srcS[ei];
    int dstv = dstS[ei];
    int rv   = rS[ei];
    int nrmv = __float_as_int(normS[ei]);

    int e = e0, i = 0;
    int sn0 = __builtin_amdgcn_readlane(srcv, 0);
    float xv = x[(size_t)sn0 * 64 + lane];          // prefetched row for edge e

    while (e < eend) {
        int r = __builtin_amdgcn_readlane(rv, i);
        int segEnd = offs[r + 1]; if (segEnd > eend) segEnd = eend;

        const f32x4* __restrict__ W4 =
            (const f32x4*)(Wt + ((size_t)r * 64 + lane) * 64);
        f32x4 w[16];
#pragma unroll
        for (int g = 0; g < 16; ++g) { w[g] = W4[g]; PIN(w[g]); }

        while (e < segEnd) {
            int   dn  = __builtin_amdgcn_readlane(dstv, i);
            float nrm = __int_as_float(__builtin_amdgcn_readlane(nrmv, i));
            int   xci = __float_as_int(xv);
            if (e + 1 < eend) {
                int sn2 = __builtin_amdgcn_readlane(srcv, i + 1);
                xv = x[(size_t)sn2 * 64 + lane];
            }
            float a0 = 0.f, a1 = 0.f, a2 = 0.f, a3 = 0.f;
#pragma unroll
            for (int g = 0; g < 16; ++g) {
                int k = g * 4;
                a0 = fmaf(__int_as_float(__builtin_amdgcn_readlane(xci, k)),     w[g].x, a0);
                a1 = fmaf(__int_as_float(__builtin_amdgcn_readlane(xci, k + 1)), w[g].y, a1);
                a2 = fmaf(__int_as_float(__builtin_amdgcn_readlane(xci, k + 2)), w[g].z, a2);
                a3 = fmaf(__int_as_float(__builtin_amdgcn_readlane(xci, k + 3)), w[g].w, a3);
            }
            atomicAdd(&s[(size_t)dn * 64 + lane], ((a0 + a1) + (a2 + a3)) * nrm);
            ++e; ++i;
        }
    }
}

// out[n] = s[n]/max(cnt,1) + x[n]@root + bias.  rootT pinned in VGPRs.
// Optionally zeroes s for the next layer. In-place-safe (row-local).
__global__ __launch_bounds__(256, 4) void node_reg(
    const float* __restrict__ x, float* __restrict__ s,
    const float* __restrict__ cnt, const float* __restrict__ rT,
    const float* __restrict__ bias, float* __restrict__ out, int zero_s)
{
    int wave = blockIdx.x * 4 + (threadIdx.x >> 6);
    int lane = threadIdx.x & 63;
    int n0 = wave * NPW;
    if (n0 >= NN) return;
    int n1 = n0 + NPW < NN ? n0 + NPW : NN;

    const f32x4* __restrict__ R4 = (const f32x4*)(rT + (size_t)lane * 64);
    f32x4 w[16];
#pragma unroll
    for (int g = 0; g < 16; ++g) { w[g] = R4[g]; PIN(w[g]); }
    float bv = bias[lane];

    float xv = x[(size_t)n0 * 64 + lane];
    float sv = s[(size_t)n0 * 64 + lane];
    for (int n = n0; n < n1; ++n) {
        int   xci  = __float_as_int(xv);
        float scur = sv;
        if (n + 1 < n1) {
            xv = x[(size_t)(n + 1) * 64 + lane];
            sv = s[(size_t)(n + 1) * 64 + lane];
        }
        float cv = cnt[n];
        float a0 = 0.f, a1 = 0.f, a2 = 0.f, a3 = 0.f;
#pragma unroll
        for (int g = 0; g < 16; ++g) {
            int k = g * 4;
            a0 = fmaf(__int_as_float(__builtin_amdgcn_readlane(xci, k)),     w[g].x, a0);
            a1 = fmaf(__int_as_float(__builtin_amdgcn_readlane(xci, k + 1)), w[g].y, a1);
            a2 = fmaf(__int_as_float(__builtin_amdgcn_readlane(xci, k + 2)), w[g].z, a2);
            a3 = fmaf(__int_as_float(__builtin_amdgcn_readlane(xci, k + 3)), w[g].w, a3);
        }
        float c = cv > 1.f ? cv : 1.f;
        out[(size_t)n * 64 + lane] = scur / c + ((a0 + a1) + (a2 + a3)) + bv;
        if (zero_s) s[(size_t)n * 64 + lane] = 0.f;
    }
}

extern "C" void kernel_launch(void* const* d_in, const int* in_sizes, int n_in,
                              void* d_out, int out_size, void* d_ws, size_t ws_size,
                              hipStream_t stream) {
    const int*   entity    = (const int*)d_in[0];
    const int*   edge_index= (const int*)d_in[1];    // [2, NE]
    const int*   edge_type = (const int*)d_in[2];
    const float* edge_norm = (const float*)d_in[3];
    const float* emb       = (const float*)d_in[4];
    const float* basis1    = (const float*)d_in[5];
    const float* att1      = (const float*)d_in[6];
    const float* root1     = (const float*)d_in[7];
    const float* bias1     = (const float*)d_in[8];
    const float* basis2    = (const float*)d_in[9];
    const float* att2      = (const float*)d_in[10];
    const float* root2     = (const float*)d_in[11];
    const float* bias2     = (const float*)d_in[12];

    const int* src = edge_index;
    const int* dst = edge_index + NE;

    // float arrays first (16B alignment for f32x4 loads), ints at the end
    float* ws    = (float*)d_ws;
    float* Wt1   = ws;                           // NR*4096
    float* Wt2   = Wt1 + (size_t)NR * 4096;      // NR*4096
    float* rT1   = Wt2 + (size_t)NR * 4096;      // 4096
    float* rT2   = rT1 + 4096;                   // 4096
    float* x0    = rT2 + 4096;                   // NN*D
    float* s     = x0  + (size_t)NN * D;         // NN*D
    float* cnt   = s   + (size_t)NN * D;         // NN
    float* normS = cnt + NN;                     // NE
    int*   offs      = (int*)(normS + NE);       // NR+1
    int*   blockHist = offs + NR + 4;            // HB*NR
    int*   blockBase = blockHist + HB * NR;      // HB*NR
    int*   srcS      = blockBase + HB * NR;      // NE
    int*   dstS      = srcS + NE;                // NE
    int*   rS        = dstS + NE;                // NE

    float* out = (float*)d_out;

    // zero s + cnt (contiguous)
    hipMemsetAsync(s, 0, ((size_t)NN * D + NN) * sizeof(float), stream);

    compute_wt<<<2 * NR + 2, 256, 0, stream>>>(att1, basis1, root1,
                                               att2, basis2, root2,
                                               Wt1, Wt2, rT1, rT2);
    gather_emb<<<(NN * 16 + 255) / 256, 256, 0, stream>>>(
        entity, (const f32x4*)emb, (f32x4*)x0);
    hist_edges<<<HB, 256, 0, stream>>>(edge_type, dst, blockHist, cnt);
    scan_blocks<<<1, 128, 0, stream>>>(blockHist, blockBase, offs);
    scatter_sorted<<<HB, 256, 0, stream>>>(src, dst, edge_type, edge_norm,
                                           blockBase, srcS, dstS, rS, normS);

    // ---- layer 1 ----
    edge_reg<<<EB, 256, 0, stream>>>(srcS, dstS, rS, normS, offs, x0, Wt1, s);
    node_reg<<<NBK, 256, 0, stream>>>(x0, s, cnt, rT1, bias1, out, 1);

    // ---- layer 2 ----
    edge_reg<<<EB, 256, 0, stream>>>(srcS, dstS, rS, normS, offs, out, Wt2, s);
    node_reg<<<NBK, 256, 0, stream>>>(out, s, cnt, rT2, bias2, out, 0);
}